// Round 1
// baseline (3889.539 us; speedup 1.0000x reference)
//
#include <hip/hip_runtime.h>
#include <math.h>

#define DIMC 64
#define HIDC 32
#define IMH 512
#define IMW 512
#define NBATCH 4
#define TILE 16
#define HALO 18
#define NPIX (HALO*HALO)   // 324
#define PLANE (IMH*IMW)

__global__ __launch_bounds__(256, 1)
void ffn_fused_kernel(const float* __restrict__ x,
                      const float* __restrict__ w1,    // [64][64]
                      const float* __restrict__ wdw,   // [64][1][3][3]
                      const float* __restrict__ w2,    // [64][32]
                      const float* __restrict__ wf,    // [64][1][1][4][3]
                      float* __restrict__ out)
{
    __shared__ float ts[DIMC * NPIX];   // conv1 output over halo tile; reused as y-buffer in freq fallback
    __shared__ float vs[HIDC * 256];    // gated hidden activations
    __shared__ int s_ident;

    const int tid = threadIdx.x;
    const int bid = blockIdx.x;
    const int tpr = IMW / TILE;          // 32
    const int tpi = (IMH / TILE) * tpr;  // 1024
    const int b  = bid / tpi;
    const int tr = bid % tpi;
    const int ty = tr / tpr, tx = tr % tpr;
    const int oy = ty * TILE, ox = tx * TILE;

    if (tid == 0) s_ident = 1;
    __syncthreads();
    // w_freq == all ones  ->  rfft2/irfft2 block is an exact identity
    if (tid < DIMC) {
        bool idf = true;
        #pragma unroll
        for (int k = 0; k < 12; ++k) idf = idf && (wf[tid * 12 + k] == 1.0f);
        if (!idf) atomicAnd(&s_ident, 0);
    }

    const float* xb = x + (size_t)b * DIMC * PLANE;

    // ---------------- Stage A: t = conv1x1(x, w1) over 18x18 halo -> LDS ----------------
    for (int p = tid; p < NPIX; p += 256) {
        const int hy = p / HALO, hx = p % HALO;
        const int gy = oy + hy - 1, gx = ox + hx - 1;
        if ((unsigned)gy >= IMH || (unsigned)gx >= IMW) {
            for (int o = 0; o < DIMC; ++o) ts[o * NPIX + p] = 0.0f;  // zero pad for dwconv
        } else {
            float acc[DIMC];
            #pragma unroll
            for (int o = 0; o < DIMC; ++o) acc[o] = 0.0f;
            const float* xp = xb + (size_t)gy * IMW + gx;
            #pragma unroll 4
            for (int c = 0; c < DIMC; ++c) {
                const float xc = xp[(size_t)c * PLANE];
                #pragma unroll
                for (int o = 0; o < DIMC; ++o)
                    acc[o] = fmaf(w1[o * DIMC + c], xc, acc[o]);
            }
            #pragma unroll
            for (int o = 0; o < DIMC; ++o) ts[o * NPIX + p] = acc[o];
        }
    }
    __syncthreads();

    // ---------------- Stage B/C: depthwise 3x3 + exact-GELU gate -> vs ----------------
    const int li = tid / TILE, lj = tid % TILE;
    for (int ch = 0; ch < HIDC; ++ch) {
        float u1 = 0.0f, u2 = 0.0f;
        #pragma unroll
        for (int di = 0; di < 3; ++di) {
            #pragma unroll
            for (int dj = 0; dj < 3; ++dj) {
                const int hp = (li + di) * HALO + (lj + dj);
                u1 = fmaf(wdw[ch * 9 + di * 3 + dj],          ts[ch * NPIX + hp],          u1);
                u2 = fmaf(wdw[(ch + HIDC) * 9 + di * 3 + dj], ts[(ch + HIDC) * NPIX + hp], u2);
            }
        }
        const float g = 0.5f * u1 * (1.0f + erff(u1 * 0.70710678118654752f));
        vs[ch * 256 + tid] = g * u2;
    }
    __syncthreads();

    // ---------------- Stage D: y = conv1x1(v, w2) ----------------
    float acc[DIMC];
    #pragma unroll
    for (int o = 0; o < DIMC; ++o) acc[o] = 0.0f;
    #pragma unroll 4
    for (int c = 0; c < HIDC; ++c) {
        const float vc = vs[c * 256 + tid];
        #pragma unroll
        for (int o = 0; o < DIMC; ++o)
            acc[o] = fmaf(w2[o * HIDC + c], vc, acc[o]);
    }

    // ---------------- Stage E/F: freq block (+shortcut) and store ----------------
    float* ob = out + (size_t)b * DIMC * PLANE;
    if (s_ident) {
        const size_t pix = (size_t)(oy + li) * IMW + (ox + lj);
        const float* xs = xb + pix;
        float* op = ob + pix;
        #pragma unroll 8
        for (int o = 0; o < DIMC; ++o)
            op[(size_t)o * PLANE] = acc[o] + xs[(size_t)o * PLANE];
    } else {
        // general path: per-4x4-patch rfft2 -> x w_freq -> irfft2 (hand-coded 4-point DFTs)
        #pragma unroll
        for (int o = 0; o < DIMC; ++o) ts[o * 256 + tid] = acc[o];   // ts reused as y[64][16][16]
        __syncthreads();
        for (int task = tid; task < 16 * DIMC; task += 256) {
            const int ch = task / 16;
            const int pt = task % 16;
            const int pi = (pt / 4) * 4, pj = (pt % 4) * 4;
            float yv[4][4];
            #pragma unroll
            for (int a = 0; a < 4; ++a)
                #pragma unroll
                for (int c = 0; c < 4; ++c)
                    yv[a][c] = ts[ch * 256 + (pi + a) * 16 + (pj + c)];
            // column DFT (over rows i), twiddles in {1,-i,-1,i}
            float Cr[4][4], Ci[4][4];
            #pragma unroll
            for (int j = 0; j < 4; ++j) {
                const float s02 = yv[0][j] + yv[2][j], d02 = yv[0][j] - yv[2][j];
                const float s13 = yv[1][j] + yv[3][j], d13 = yv[1][j] - yv[3][j];
                Cr[0][j] = s02 + s13; Ci[0][j] = 0.0f;
                Cr[1][j] = d02;       Ci[1][j] = -d13;
                Cr[2][j] = s02 - s13; Ci[2][j] = 0.0f;
                Cr[3][j] = d02;       Ci[3][j] = d13;
            }
            // row rfft (over cols j), keep v = 0..2; multiply by w_freq
            float Zr[4][3], Zi[4][3];
            #pragma unroll
            for (int u = 0; u < 4; ++u) {
                const float r0 = Cr[u][0], r1 = Cr[u][1], r2 = Cr[u][2], r3 = Cr[u][3];
                const float i0 = Ci[u][0], i1 = Ci[u][1], i2 = Ci[u][2], i3 = Ci[u][3];
                Zr[u][0] = r0 + r1 + r2 + r3;            Zi[u][0] = i0 + i1 + i2 + i3;
                Zr[u][1] = (r0 - r2) + (i1 - i3);        Zi[u][1] = (i0 - i2) - (r1 - r3);
                Zr[u][2] = r0 - r1 + r2 - r3;            Zi[u][2] = i0 - i1 + i2 - i3;
                #pragma unroll
                for (int v = 0; v < 3; ++v) {
                    const float m = wf[ch * 12 + u * 3 + v];
                    Zr[u][v] *= m; Zi[u][v] *= m;
                }
            }
            // inverse column ifft (over u), unnormalized
            float Ar[4][3], Ai[4][3];
            #pragma unroll
            for (int v = 0; v < 3; ++v) {
                const float r0 = Zr[0][v], r1 = Zr[1][v], r2 = Zr[2][v], r3 = Zr[3][v];
                const float i0 = Zi[0][v], i1 = Zi[1][v], i2 = Zi[2][v], i3 = Zi[3][v];
                Ar[0][v] = r0 + r1 + r2 + r3;        Ai[0][v] = i0 + i1 + i2 + i3;
                Ar[1][v] = (r0 - r2) - (i1 - i3);    Ai[1][v] = (i0 - i2) + (r1 - r3);
                Ar[2][v] = r0 - r1 + r2 - r3;        Ai[2][v] = i0 - i1 + i2 - i3;
                Ar[3][v] = (r0 - r2) + (i1 - i3);    Ai[3][v] = (i0 - i2) - (r1 - r3);
            }
            // final row irfft: res[a][b'] = (A0 + 2*(Ar1*cos - Ai1*sin) + A2*(-1)^b') / 16
            const float* xc = xb + (size_t)ch * PLANE;
            float*       oc = ob + (size_t)ch * PLANE;
            #pragma unroll
            for (int a = 0; a < 4; ++a) {
                const float A0 = Ar[a][0], A1r = Ar[a][1], A1i = Ar[a][2 - 1], A2 = Ar[a][2];
                const float B1i = Ai[a][1];
                float res[4];
                res[0] = (A0 + 2.0f * A1r + A2) * 0.0625f;
                res[1] = (A0 - 2.0f * B1i - A2) * 0.0625f;
                res[2] = (A0 - 2.0f * A1r + A2) * 0.0625f;
                res[3] = (A0 + 2.0f * B1i - A2) * 0.0625f;
                (void)A1i;
                #pragma unroll
                for (int c = 0; c < 4; ++c) {
                    const size_t pix = (size_t)(oy + pi + a) * IMW + (ox + pj + c);
                    oc[pix] = res[c] + xc[pix];
                }
            }
        }
    }
}

extern "C" void kernel_launch(void* const* d_in, const int* in_sizes, int n_in,
                              void* d_out, int out_size, void* d_ws, size_t ws_size,
                              hipStream_t stream) {
    (void)in_sizes; (void)n_in; (void)d_ws; (void)ws_size; (void)out_size;
    const float* x   = (const float*)d_in[0];
    const float* w1  = (const float*)d_in[1];
    const float* wdw = (const float*)d_in[2];
    const float* w2  = (const float*)d_in[3];
    const float* wf  = (const float*)d_in[4];
    float* out = (float*)d_out;

    const int blocks = NBATCH * (IMH / TILE) * (IMW / TILE);  // 4096
    ffn_fused_kernel<<<blocks, 256, 0, stream>>>(x, w1, wdw, w2, wf, out);
}

// Round 2
// 462.997 us; speedup vs baseline: 8.4008x; 8.4008x over previous
//
#include <hip/hip_runtime.h>
#include <math.h>

#define DIMC 64
#define HIDC 32
#define IMH 512
#define IMW 512
#define NBATCH 4
#define TILE 16
#define HALO 18
#define NPIX (HALO*HALO)     // 324
#define NPIXP 336            // padded to 21 chunks of 16
#define NCHUNK 21
#define TSTRIDE 35           // 32-bit words per pixel (70 bf16 elems = 140 B): bank = (3*px + ch) % 32
#define PLANE (IMH*IMW)

typedef short short8 __attribute__((ext_vector_type(8)));
typedef float f32x4  __attribute__((ext_vector_type(4)));

static __device__ __forceinline__ unsigned f2bf(float f) {
    union { float f; unsigned u; } v; v.f = f;
    return (v.u + 0x7fffu + ((v.u >> 16) & 1u)) >> 16;   // RNE bf16, low 16 bits
}
static __device__ __forceinline__ float bf2f(unsigned s) {
    union { unsigned u; float f; } v; v.u = s << 16;
    return v.f;
}

__global__ __launch_bounds__(256, 3)
void ffn_fused_kernel(const float* __restrict__ x,
                      const float* __restrict__ w1,    // [64][64]
                      const float* __restrict__ wdw,   // [64][1][3][3]
                      const float* __restrict__ w2,    // [64][32]
                      const float* __restrict__ wf,    // [64][1][1][4][3]
                      float* __restrict__ out)
{
    __shared__ unsigned ts[NPIXP * TSTRIDE];   // 47040 B: x halo (bf16 pairs), then t pairs, then f32 scratch (fallback)
    __shared__ int s_ident;

    const int tid = threadIdx.x;
    const int bid = blockIdx.x;
    const int tpr = IMW / TILE;           // 32
    const int tpi = (IMH / TILE) * tpr;   // 1024
    const int b  = bid / tpi;
    const int tr = bid % tpi;
    const int ty = tr / tpr, tx = tr % tpr;
    const int oy = ty * TILE, ox = tx * TILE;

    if (tid == 0) s_ident = 1;
    __syncthreads();
    if (tid < DIMC) {
        bool idf = true;
        #pragma unroll
        for (int k = 0; k < 12; ++k) idf = idf && (wf[tid * 12 + k] == 1.0f);
        if (!idf) atomicAnd(&s_ident, 0);
    }

    const float* xb = x + (size_t)b * DIMC * PLANE;

    // ---------- Stage 0: stage x halo -> LDS bf16, layout [px][ch] packed pairs (c,c+1) ----------
    for (int p = tid; p < NPIX; p += 256) {
        const int hy = p / HALO, hx = p % HALO;
        const int gy = oy + hy - 1, gx = ox + hx - 1;
        unsigned* row = &ts[p * TSTRIDE];
        if ((unsigned)gy >= IMH || (unsigned)gx >= IMW) {
            #pragma unroll
            for (int w = 0; w < 32; ++w) row[w] = 0u;
        } else {
            const float* xp = xb + (size_t)gy * IMW + gx;
            #pragma unroll
            for (int c0 = 0; c0 < DIMC; c0 += 8) {
                float f[8];
                #pragma unroll
                for (int i = 0; i < 8; ++i) f[i] = xp[(size_t)(c0 + i) * PLANE];
                #pragma unroll
                for (int i = 0; i < 8; i += 2)
                    row[(c0 + i) >> 1] = f2bf(f[i]) | (f2bf(f[i + 1]) << 16);
            }
        }
    }

    // ---------- A-fragments of W1 (bf16) : lane l -> row = mt*16 + (l&15), k = ks*32 + (l>>4)*8 + j ----------
    const int lane = tid & 63, wid = tid >> 6;
    const int l15 = lane & 15, lg = lane >> 4;
    short8 afrag[4][2];
    #pragma unroll
    for (int mt = 0; mt < 4; ++mt) {
        #pragma unroll
        for (int ks = 0; ks < 2; ++ks) {
            const float* wp = w1 + (size_t)(mt * 16 + l15) * DIMC + ks * 32 + lg * 8;
            f32x4 wa = *reinterpret_cast<const f32x4*>(wp);
            f32x4 wb = *reinterpret_cast<const f32x4*>(wp + 4);
            short8 s;
            #pragma unroll
            for (int j = 0; j < 4; ++j) { s[j] = (short)f2bf(wa[j]); s[j + 4] = (short)f2bf(wb[j]); }
            afrag[mt][ks] = s;
        }
    }
    __syncthreads();

    // ---------- Stage A: t = W1 * x via MFMA, per-wave pixel chunks, in-place t write (pair layout) ----------
    for (int chunk = wid; chunk < NCHUNK; chunk += 4) {
        const int px = chunk * 16 + l15;
        const unsigned base = px * TSTRIDE;
        f32x4 acc[4];
        #pragma unroll
        for (int mt = 0; mt < 4; ++mt) acc[mt] = (f32x4)0.0f;
        #pragma unroll
        for (int ks = 0; ks < 2; ++ks) {
            union { unsigned u[4]; short8 s; } bw;
            #pragma unroll
            for (int t = 0; t < 4; ++t) bw.u[t] = ts[base + ks * 16 + lg * 4 + t];
            #pragma unroll
            for (int mt = 0; mt < 4; ++mt)
                acc[mt] = __builtin_amdgcn_mfma_f32_16x16x32_bf16(afrag[mt][ks], bw.s, acc[mt], 0, 0, 0);
        }
        // D: row(ch within tile) = lg*4 + r, col(px) = l15. Write pairs (ch, ch+32) -> word px*35 + ch
        #pragma unroll
        for (int mt = 0; mt < 2; ++mt) {
            #pragma unroll
            for (int r = 0; r < 4; ++r) {
                const int chA = mt * 16 + lg * 4 + r;
                ts[base + chA] = f2bf(acc[mt][r]) | (f2bf(acc[mt + 2][r]) << 16);
            }
        }
    }
    __syncthreads();

    // ---------- Stage B: depthwise 3x3 + exact-GELU gate -> v[32] in registers ----------
    const int li = tid >> 4, lj = tid & 15;
    float v[HIDC];
    #pragma unroll 4
    for (int ch = 0; ch < HIDC; ++ch) {
        float u1 = 0.0f, u2 = 0.0f;
        #pragma unroll
        for (int di = 0; di < 3; ++di) {
            #pragma unroll
            for (int dj = 0; dj < 3; ++dj) {
                const unsigned u = ts[((li + di) * HALO + (lj + dj)) * TSTRIDE + ch];
                u1 = fmaf(wdw[ch * 9 + di * 3 + dj],          bf2f(u & 0xffffu), u1);
                u2 = fmaf(wdw[(ch + HIDC) * 9 + di * 3 + dj], bf2f(u >> 16),     u2);
            }
        }
        const float g = 0.5f * u1 * (1.0f + erff(u1 * 0.70710678118654752f));
        v[ch] = g * u2;
    }

    // ---------- Stage D: y = W2 * v (VALU, w2 rows contiguous -> vector s_loads) ----------
    float acc2[DIMC];
    #pragma unroll 8
    for (int o = 0; o < DIMC; ++o) {
        float a = 0.0f;
        #pragma unroll
        for (int c = 0; c < HIDC; ++c) a = fmaf(w2[o * HIDC + c], v[c], a);
        acc2[o] = a;
    }

    // ---------- Stage E: freq block (+shortcut) and store ----------
    float* ob = out + (size_t)b * DIMC * PLANE;
    if (s_ident) {
        const size_t pix = (size_t)(oy + li) * IMW + (ox + lj);
        const float* xs = xb + pix;
        float* op = ob + pix;
        #pragma unroll 8
        for (int o = 0; o < DIMC; ++o)
            op[(size_t)o * PLANE] = acc2[o] + xs[(size_t)o * PLANE];
    } else {
        // general path: per-4x4-patch rfft2 -> x w_freq -> irfft2, two channel halves through LDS
        float* ys = (float*)ts;   // 32*257*4 = 32896 B <= 47040
        for (int half = 0; half < 2; ++half) {
            __syncthreads();
            #pragma unroll
            for (int c = 0; c < 32; ++c) ys[c * 257 + tid] = acc2[half * 32 + c];
            __syncthreads();
            for (int task = tid; task < 512; task += 256) {
                const int chl = task >> 4;
                const int ch  = half * 32 + chl;
                const int pt  = task & 15;
                const int pi = (pt >> 2) * 4, pj = (pt & 3) * 4;
                float yv[4][4];
                #pragma unroll
                for (int a = 0; a < 4; ++a)
                    #pragma unroll
                    for (int c = 0; c < 4; ++c)
                        yv[a][c] = ys[chl * 257 + (pi + a) * 16 + (pj + c)];
                float Cr[4][4], Ci[4][4];
                #pragma unroll
                for (int j = 0; j < 4; ++j) {
                    const float s02 = yv[0][j] + yv[2][j], d02 = yv[0][j] - yv[2][j];
                    const float s13 = yv[1][j] + yv[3][j], d13 = yv[1][j] - yv[3][j];
                    Cr[0][j] = s02 + s13; Ci[0][j] = 0.0f;
                    Cr[1][j] = d02;       Ci[1][j] = -d13;
                    Cr[2][j] = s02 - s13; Ci[2][j] = 0.0f;
                    Cr[3][j] = d02;       Ci[3][j] = d13;
                }
                float Zr[4][3], Zi[4][3];
                #pragma unroll
                for (int u = 0; u < 4; ++u) {
                    const float r0 = Cr[u][0], r1 = Cr[u][1], r2 = Cr[u][2], r3 = Cr[u][3];
                    const float i0 = Ci[u][0], i1 = Ci[u][1], i2 = Ci[u][2], i3 = Ci[u][3];
                    Zr[u][0] = r0 + r1 + r2 + r3;     Zi[u][0] = i0 + i1 + i2 + i3;
                    Zr[u][1] = (r0 - r2) + (i1 - i3); Zi[u][1] = (i0 - i2) - (r1 - r3);
                    Zr[u][2] = r0 - r1 + r2 - r3;     Zi[u][2] = i0 - i1 + i2 - i3;
                    #pragma unroll
                    for (int vv = 0; vv < 3; ++vv) {
                        const float m = wf[ch * 12 + u * 3 + vv];
                        Zr[u][vv] *= m; Zi[u][vv] *= m;
                    }
                }
                float Ar[4][3], Ai[4][3];
                #pragma unroll
                for (int vv = 0; vv < 3; ++vv) {
                    const float r0 = Zr[0][vv], r1 = Zr[1][vv], r2 = Zr[2][vv], r3 = Zr[3][vv];
                    const float i0 = Zi[0][vv], i1 = Zi[1][vv], i2 = Zi[2][vv], i3 = Zi[3][vv];
                    Ar[0][vv] = r0 + r1 + r2 + r3;     Ai[0][vv] = i0 + i1 + i2 + i3;
                    Ar[1][vv] = (r0 - r2) - (i1 - i3); Ai[1][vv] = (i0 - i2) + (r1 - r3);
                    Ar[2][vv] = r0 - r1 + r2 - r3;     Ai[2][vv] = i0 - i1 + i2 - i3;
                    Ar[3][vv] = (r0 - r2) + (i1 - i3); Ai[3][vv] = (i0 - i2) - (r1 - r3);
                }
                const float* xc = xb + (size_t)ch * PLANE;
                float*       oc = ob + (size_t)ch * PLANE;
                #pragma unroll
                for (int a = 0; a < 4; ++a) {
                    const float A0 = Ar[a][0], A1r = Ar[a][1], A2 = Ar[a][2];
                    const float B1i = Ai[a][1];
                    float res[4];
                    res[0] = (A0 + 2.0f * A1r + A2) * 0.0625f;
                    res[1] = (A0 - 2.0f * B1i - A2) * 0.0625f;
                    res[2] = (A0 - 2.0f * A1r + A2) * 0.0625f;
                    res[3] = (A0 + 2.0f * B1i - A2) * 0.0625f;
                    #pragma unroll
                    for (int c = 0; c < 4; ++c) {
                        const size_t pix = (size_t)(oy + pi + a) * IMW + (ox + pj + c);
                        oc[pix] = res[c] + xc[pix];
                    }
                }
            }
        }
    }
}

extern "C" void kernel_launch(void* const* d_in, const int* in_sizes, int n_in,
                              void* d_out, int out_size, void* d_ws, size_t ws_size,
                              hipStream_t stream) {
    (void)in_sizes; (void)n_in; (void)d_ws; (void)ws_size; (void)out_size;
    const float* x   = (const float*)d_in[0];
    const float* w1  = (const float*)d_in[1];
    const float* wdw = (const float*)d_in[2];
    const float* w2  = (const float*)d_in[3];
    const float* wf  = (const float*)d_in[4];
    float* out = (float*)d_out;

    const int blocks = NBATCH * (IMH / TILE) * (IMW / TILE);  // 4096
    ffn_fused_kernel<<<blocks, 256, 0, stream>>>(x, w1, wdw, w2, wf, out);
}

// Round 3
// 256.257 us; speedup vs baseline: 15.1783x; 1.8068x over previous
//
#include <hip/hip_runtime.h>
#include <math.h>

#define DIMC 64
#define HIDC 32
#define IMH 512
#define IMW 512
#define NBATCH 4
#define TW 32
#define TH 8
#define HW 34
#define HH 10
#define NPIX (HW*HH)       // 340
#define NPIXP 352          // 22 chunks of 16
#define NCHUNK 22
#define TSTRIDE 35         // u32 words per pixel: bank = (3*px + w) % 32 -> conflict-free patterns
#define PLANE (IMH*IMW)

typedef short short8 __attribute__((ext_vector_type(8)));
typedef float f32x4  __attribute__((ext_vector_type(4)));

static __device__ __forceinline__ unsigned f2bf(float f) {
    union { float f; unsigned u; } v; v.f = f;
    return (v.u + 0x7fffu + ((v.u >> 16) & 1u)) >> 16;   // RNE bf16
}
static __device__ __forceinline__ float bf2f(unsigned s) {
    union { unsigned u; float f; } v; v.u = s << 16;
    return v.f;
}

__global__ __launch_bounds__(256, 3)
void ffn_fused_kernel(const float* __restrict__ x,
                      const float* __restrict__ w1,    // [64][64]
                      const float* __restrict__ wdw,   // [64][1][3][3]
                      const float* __restrict__ w2,    // [64][32]
                      const float* __restrict__ wf,    // [64][1][1][4][3]
                      float* __restrict__ out)
{
    __shared__ unsigned ts[NPIXP * TSTRIDE];   // 49280 B: x halo bf16 pairs -> overwritten by t pairs
    __shared__ int s_ident;

    const int tid = threadIdx.x;
    // XCD-chunked bijective swizzle (4096 % 8 == 0): each XCD gets 512 consecutive tiles
    const int bid = ((blockIdx.x & 7) << 9) + (blockIdx.x >> 3);
    const int b  = bid >> 10;                 // batch
    const int tr = bid & 1023;
    const int ty = tr >> 4, tx = tr & 15;     // 64 tile-rows x 16 tile-cols
    const int oy = ty * TH, ox = tx * TW;

    if (tid == 0) s_ident = 1;
    __syncthreads();
    if (tid < DIMC) {
        bool idf = true;
        #pragma unroll
        for (int k = 0; k < 12; ++k) idf = idf && (wf[tid * 12 + k] == 1.0f);
        if (!idf) atomicAnd(&s_ident, 0);
    }

    const float* xb = x + (size_t)b * DIMC * PLANE;

    // ---------- Stage 0: stage x halo -> LDS bf16 [px][ch] packed pairs (c,c+1) ----------
    for (int p = tid; p < NPIXP; p += 256) {
        const int hy = p / HW, hx = p % HW;
        const int gy = oy + hy - 1, gx = ox + hx - 1;
        unsigned* row = &ts[p * TSTRIDE];
        if (p >= NPIX || (unsigned)gy >= IMH || (unsigned)gx >= IMW) {
            #pragma unroll
            for (int w = 0; w < 32; ++w) row[w] = 0u;
        } else {
            const float* xp = xb + (size_t)gy * IMW + gx;
            #pragma unroll
            for (int c0 = 0; c0 < DIMC; c0 += 8) {
                float f[8];
                #pragma unroll
                for (int i = 0; i < 8; ++i) f[i] = xp[(size_t)(c0 + i) * PLANE];
                #pragma unroll
                for (int i = 0; i < 8; i += 2)
                    row[(c0 + i) >> 1] = f2bf(f[i]) | (f2bf(f[i + 1]) << 16);
            }
        }
    }

    // ---------- A-fragments of W1 (bf16): lane l -> row = mt*16+(l&15), k = ks*32+(l>>4)*8+j ----------
    const int lane = tid & 63, wid = tid >> 6;
    const int l15 = lane & 15, lg = lane >> 4;
    short8 afrag[4][2];
    #pragma unroll
    for (int mt = 0; mt < 4; ++mt) {
        #pragma unroll
        for (int ks = 0; ks < 2; ++ks) {
            const float* wp = w1 + (size_t)(mt * 16 + l15) * DIMC + ks * 32 + lg * 8;
            f32x4 wa = *reinterpret_cast<const f32x4*>(wp);
            f32x4 wb = *reinterpret_cast<const f32x4*>(wp + 4);
            short8 s;
            #pragma unroll
            for (int j = 0; j < 4; ++j) { s[j] = (short)f2bf(wa[j]); s[j + 4] = (short)f2bf(wb[j]); }
            afrag[mt][ks] = s;
        }
    }
    __syncthreads();

    // ---------- Snapshot center-pixel x (shortcut) to registers before t overwrites it ----------
    const int li = tid >> 5, lj = tid & 31;   // 8 rows x 32 cols
    unsigned xsave[32];
    {
        const unsigned pc = (unsigned)((li + 1) * HW + (lj + 1)) * TSTRIDE;
        #pragma unroll
        for (int w = 0; w < 32; ++w) xsave[w] = ts[pc + w];
    }
    __syncthreads();

    // ---------- Stage A: t = W1 * x via MFMA, in-place write as (ch, ch+32) bf16 pairs ----------
    for (int chunk = wid; chunk < NCHUNK; chunk += 4) {
        const unsigned base = (unsigned)(chunk * 16 + l15) * TSTRIDE;
        f32x4 acc[4];
        #pragma unroll
        for (int mt = 0; mt < 4; ++mt) acc[mt] = (f32x4)0.0f;
        #pragma unroll
        for (int ks = 0; ks < 2; ++ks) {
            union { unsigned u[4]; short8 s; } bw;
            #pragma unroll
            for (int t = 0; t < 4; ++t) bw.u[t] = ts[base + ks * 16 + lg * 4 + t];
            #pragma unroll
            for (int mt = 0; mt < 4; ++mt)
                acc[mt] = __builtin_amdgcn_mfma_f32_16x16x32_bf16(afrag[mt][ks], bw.s, acc[mt], 0, 0, 0);
        }
        #pragma unroll
        for (int mt = 0; mt < 2; ++mt) {
            #pragma unroll
            for (int r = 0; r < 4; ++r) {
                const int chA = mt * 16 + lg * 4 + r;
                ts[base + chA] = f2bf(acc[mt][r]) | (f2bf(acc[mt + 2][r]) << 16);
            }
        }
    }
    __syncthreads();

    // ---------- Stage B: depthwise 3x3 + exact-GELU gate -> v[32] in registers ----------
    float v[HIDC];
    #pragma unroll 4
    for (int ch = 0; ch < HIDC; ++ch) {
        float u1 = 0.0f, u2 = 0.0f;
        #pragma unroll
        for (int di = 0; di < 3; ++di) {
            #pragma unroll
            for (int dj = 0; dj < 3; ++dj) {
                const unsigned u = ts[((li + di) * HW + (lj + dj)) * TSTRIDE + ch];
                u1 = fmaf(wdw[ch * 9 + di * 3 + dj],          bf2f(u & 0xffffu), u1);
                u2 = fmaf(wdw[(ch + HIDC) * 9 + di * 3 + dj], bf2f(u >> 16),     u2);
            }
        }
        const float g = 0.5f * u1 * (1.0f + erff(u1 * 0.70710678118654752f));
        v[ch] = g * u2;
    }

    // ---------- Stage D+E: y = W2 * v, add register shortcut, store full 128B lines ----------
    float* ob = out + (size_t)b * DIMC * PLANE;
    if (s_ident) {
        const size_t pix = (size_t)(oy + li) * IMW + (ox + lj);
        float* op = ob + pix;
        #pragma unroll
        for (int og = 0; og < 8; ++og) {
            float a[8];
            #pragma unroll
            for (int j = 0; j < 8; ++j) a[j] = 0.0f;
            #pragma unroll
            for (int c = 0; c < HIDC; ++c) {
                const float vc = v[c];
                #pragma unroll
                for (int j = 0; j < 8; ++j)
                    a[j] = fmaf(w2[(og * 8 + j) * HIDC + c], vc, a[j]);
            }
            #pragma unroll
            for (int j = 0; j < 8; ++j) {
                const int o = og * 8 + j;
                const unsigned xw = xsave[o >> 1];
                const float xv = bf2f((o & 1) ? (xw >> 16) : (xw & 0xffffu));
                op[(size_t)o * PLANE] = a[j] + xv;
            }
        }
    } else {
        // general path (not hit in bench): full y, per-4x4-patch rfft2 -> x w_freq -> irfft2
        float acc2[DIMC];
        #pragma unroll 8
        for (int o = 0; o < DIMC; ++o) {
            float a = 0.0f;
            #pragma unroll
            for (int c = 0; c < HIDC; ++c) a = fmaf(w2[o * HIDC + c], v[c], a);
            acc2[o] = a;
        }
        float* ys = (float*)ts;   // 32*257*4 = 32896 B <= 49280
        for (int half = 0; half < 2; ++half) {
            __syncthreads();
            #pragma unroll
            for (int c = 0; c < 32; ++c) ys[c * 257 + tid] = acc2[half * 32 + c];
            __syncthreads();
            for (int task = tid; task < 512; task += 256) {
                const int chl = task >> 4;
                const int ch  = half * 32 + chl;
                const int pt  = task & 15;           // 2 patch-rows x 8 patch-cols
                const int pi = (pt >> 3) * 4, pj = (pt & 7) * 4;
                float yv[4][4];
                #pragma unroll
                for (int a = 0; a < 4; ++a)
                    #pragma unroll
                    for (int c = 0; c < 4; ++c)
                        yv[a][c] = ys[chl * 257 + (pi + a) * TW + (pj + c)];
                float Cr[4][4], Ci[4][4];
                #pragma unroll
                for (int j = 0; j < 4; ++j) {
                    const float s02 = yv[0][j] + yv[2][j], d02 = yv[0][j] - yv[2][j];
                    const float s13 = yv[1][j] + yv[3][j], d13 = yv[1][j] - yv[3][j];
                    Cr[0][j] = s02 + s13; Ci[0][j] = 0.0f;
                    Cr[1][j] = d02;       Ci[1][j] = -d13;
                    Cr[2][j] = s02 - s13; Ci[2][j] = 0.0f;
                    Cr[3][j] = d02;       Ci[3][j] = d13;
                }
                float Zr[4][3], Zi[4][3];
                #pragma unroll
                for (int u = 0; u < 4; ++u) {
                    const float r0 = Cr[u][0], r1 = Cr[u][1], r2 = Cr[u][2], r3 = Cr[u][3];
                    const float i0 = Ci[u][0], i1 = Ci[u][1], i2 = Ci[u][2], i3 = Ci[u][3];
                    Zr[u][0] = r0 + r1 + r2 + r3;     Zi[u][0] = i0 + i1 + i2 + i3;
                    Zr[u][1] = (r0 - r2) + (i1 - i3); Zi[u][1] = (i0 - i2) - (r1 - r3);
                    Zr[u][2] = r0 - r1 + r2 - r3;     Zi[u][2] = i0 - i1 + i2 - i3;
                    #pragma unroll
                    for (int vv = 0; vv < 3; ++vv) {
                        const float m = wf[ch * 12 + u * 3 + vv];
                        Zr[u][vv] *= m; Zi[u][vv] *= m;
                    }
                }
                float Ar[4][3], Ai[4][3];
                #pragma unroll
                for (int vv = 0; vv < 3; ++vv) {
                    const float r0 = Zr[0][vv], r1 = Zr[1][vv], r2 = Zr[2][vv], r3 = Zr[3][vv];
                    const float i0 = Zi[0][vv], i1 = Zi[1][vv], i2 = Zi[2][vv], i3 = Zi[3][vv];
                    Ar[0][vv] = r0 + r1 + r2 + r3;     Ai[0][vv] = i0 + i1 + i2 + i3;
                    Ar[1][vv] = (r0 - r2) - (i1 - i3); Ai[1][vv] = (i0 - i2) + (r1 - r3);
                    Ar[2][vv] = r0 - r1 + r2 - r3;     Ai[2][vv] = i0 - i1 + i2 - i3;
                    Ar[3][vv] = (r0 - r2) + (i1 - i3); Ai[3][vv] = (i0 - i2) - (r1 - r3);
                }
                const float* xc = xb + (size_t)ch * PLANE;
                float*       oc = ob + (size_t)ch * PLANE;
                #pragma unroll
                for (int a = 0; a < 4; ++a) {
                    const float A0 = Ar[a][0], A1r = Ar[a][1], A2 = Ar[a][2];
                    const float B1i = Ai[a][1];
                    float res[4];
                    res[0] = (A0 + 2.0f * A1r + A2) * 0.0625f;
                    res[1] = (A0 - 2.0f * B1i - A2) * 0.0625f;
                    res[2] = (A0 - 2.0f * A1r + A2) * 0.0625f;
                    res[3] = (A0 + 2.0f * B1i - A2) * 0.0625f;
                    #pragma unroll
                    for (int c = 0; c < 4; ++c) {
                        const size_t pix = (size_t)(oy + pi + a) * IMW + (ox + pj + c);
                        oc[pix] = res[c] + xc[pix];
                    }
                }
            }
        }
    }
}

extern "C" void kernel_launch(void* const* d_in, const int* in_sizes, int n_in,
                              void* d_out, int out_size, void* d_ws, size_t ws_size,
                              hipStream_t stream) {
    (void)in_sizes; (void)n_in; (void)d_ws; (void)ws_size; (void)out_size;
    const float* x   = (const float*)d_in[0];
    const float* w1  = (const float*)d_in[1];
    const float* wdw = (const float*)d_in[2];
    const float* w2  = (const float*)d_in[3];
    const float* wf  = (const float*)d_in[4];
    float* out = (float*)d_out;

    const int blocks = NBATCH * (IMH / TH) * (IMW / TW);  // 4096
    ffn_fused_kernel<<<blocks, 256, 0, stream>>>(x, w1, wdw, w2, wf, out);
}

// Round 4
// 212.930 us; speedup vs baseline: 18.2667x; 1.2035x over previous
//
#include <hip/hip_runtime.h>
#include <math.h>

#define DIMC 64
#define HIDC 32
#define IMH 512
#define IMW 512
#define NBATCH 4
#define TW 32
#define TH 8
#define HW 34
#define HH 10
#define NPIX (HW*HH)       // 340
#define NPIXP 352          // 22 chunks of 16
#define NCHUNK 22
#define TSTRIDE 35         // u32 words per halo pixel
#define VSTRIDE 17         // u32 words per pixel for v (bf16 pairs, 16 used)
#define PLANE (IMH*IMW)

typedef short short8 __attribute__((ext_vector_type(8)));
typedef float f32x4  __attribute__((ext_vector_type(4)));

static __device__ __forceinline__ unsigned cvt_pk_bf16(float lo, float hi) {
    unsigned r;
    asm("v_cvt_pk_bf16_f32 %0, %1, %2" : "=v"(r) : "v"(lo), "v"(hi));
    return r;   // low 16 = bf16(lo), high 16 = bf16(hi), RNE
}
static __device__ __forceinline__ float bf2f_lo(unsigned s) {
    union { unsigned u; float f; } v; v.u = s << 16; return v.f;
}
static __device__ __forceinline__ float bf2f_hi(unsigned s) {
    union { unsigned u; float f; } v; v.u = s & 0xffff0000u; return v.f;
}
static __device__ __forceinline__ unsigned f2bf(float f) {
    union { float f; unsigned u; } v; v.f = f;
    return (v.u + 0x7fffu + ((v.u >> 16) & 1u)) >> 16;
}

// exact-enough GELU: erf via Abramowitz-Stegun 7.1.26 (|eps| < 1.5e-7), branchless
static __device__ __forceinline__ float gelu_f(float u) {
    const float z  = fabsf(u) * 0.70710678118654752f;
    const float t  = __builtin_amdgcn_rcpf(fmaf(0.3275911f, z, 1.0f));
    const float e  = __builtin_amdgcn_exp2f(-z * z * 1.4426950408889634f);
    float p = fmaf(t, 1.061405429f, -1.453152027f);
    p = fmaf(t, p, 1.421413741f);
    p = fmaf(t, p, -0.284496736f);
    p = fmaf(t, p, 0.254829592f);
    p = p * t;
    const float erf_abs = fmaf(-p, e, 1.0f);
    const float erfv = copysignf(erf_abs, u);
    return 0.5f * u * (1.0f + erfv);
}

__global__ __launch_bounds__(256, 3)
void ffn_fused_kernel(const float* __restrict__ x,
                      const float* __restrict__ w1,    // [64][64]
                      const float* __restrict__ wdw,   // [64][1][3][3]
                      const float* __restrict__ w2,    // [64][32]
                      const float* __restrict__ wf,    // [64][1][1][4][3]
                      float* __restrict__ out)
{
    __shared__ unsigned ts[NPIXP * TSTRIDE];   // 49280 B
    __shared__ int s_ident;

    const int tid = threadIdx.x;
    // XCD-chunked bijective swizzle (4096 % 8 == 0)
    const int bid = ((blockIdx.x & 7) << 9) + (blockIdx.x >> 3);
    const int b  = bid >> 10;
    const int tr = bid & 1023;
    const int ty = tr >> 4, tx = tr & 15;     // 64 tile-rows x 16 tile-cols
    const int oy = ty * TH, ox = tx * TW;

    if (tid == 0) s_ident = 1;
    __syncthreads();
    if (tid < DIMC) {
        bool idf = true;
        #pragma unroll
        for (int k = 0; k < 12; ++k) idf = idf && (wf[tid * 12 + k] == 1.0f);
        if (!idf) atomicAnd(&s_ident, 0);
    }

    const float* xb = x + (size_t)b * DIMC * PLANE;

    // ---------- Stage 0: stage x halo -> LDS bf16 [px][ch] packed pairs ----------
    for (int p = tid; p < NPIXP; p += 256) {
        const int hy = p / HW, hx = p % HW;
        const int gy = oy + hy - 1, gx = ox + hx - 1;
        unsigned* row = &ts[p * TSTRIDE];
        if (p >= NPIX || (unsigned)gy >= IMH || (unsigned)gx >= IMW) {
            #pragma unroll
            for (int w = 0; w < 32; ++w) row[w] = 0u;
        } else {
            const float* xp = xb + (size_t)gy * IMW + gx;
            #pragma unroll
            for (int c0 = 0; c0 < DIMC; c0 += 8) {
                float f[8];
                #pragma unroll
                for (int i = 0; i < 8; ++i) f[i] = xp[(size_t)(c0 + i) * PLANE];
                #pragma unroll
                for (int i = 0; i < 8; i += 2)
                    row[(c0 + i) >> 1] = cvt_pk_bf16(f[i], f[i + 1]);
            }
        }
    }

    const int lane = tid & 63, wid = tid >> 6;
    const int l15 = lane & 15, lg = lane >> 4;

    // ---------- A-fragments: W1 (K=64 -> 2 k-steps) and W2 (K=32) ----------
    short8 afrag1[4][2];
    #pragma unroll
    for (int mt = 0; mt < 4; ++mt) {
        #pragma unroll
        for (int ks = 0; ks < 2; ++ks) {
            const float* wp = w1 + (size_t)(mt * 16 + l15) * DIMC + ks * 32 + lg * 8;
            f32x4 wa = *reinterpret_cast<const f32x4*>(wp);
            f32x4 wb = *reinterpret_cast<const f32x4*>(wp + 4);
            union { unsigned u[4]; short8 s; } pk;
            pk.u[0] = cvt_pk_bf16(wa[0], wa[1]); pk.u[1] = cvt_pk_bf16(wa[2], wa[3]);
            pk.u[2] = cvt_pk_bf16(wb[0], wb[1]); pk.u[3] = cvt_pk_bf16(wb[2], wb[3]);
            afrag1[mt][ks] = pk.s;
        }
    }
    short8 afrag2[4];
    #pragma unroll
    for (int mt = 0; mt < 4; ++mt) {
        const float* wp = w2 + (size_t)(mt * 16 + l15) * HIDC + lg * 8;
        f32x4 wa = *reinterpret_cast<const f32x4*>(wp);
        f32x4 wb = *reinterpret_cast<const f32x4*>(wp + 4);
        union { unsigned u[4]; short8 s; } pk;
        pk.u[0] = cvt_pk_bf16(wa[0], wa[1]); pk.u[1] = cvt_pk_bf16(wa[2], wa[3]);
        pk.u[2] = cvt_pk_bf16(wb[0], wb[1]); pk.u[3] = cvt_pk_bf16(wb[2], wb[3]);
        afrag2[mt] = pk.s;
    }
    __syncthreads();

    // ---------- Snapshot shortcut x in STORE-side layout (before t overwrites it) ----------
    // store: lane needs x[ch = mt*16+lg*4+r][px = wid*64 + cc*16 + l15]
    unsigned xs[4][4][2];   // [cc][mt][word]; word w holds channels (16mt+4lg+2w, +1)
    #pragma unroll
    for (int cc = 0; cc < 4; ++cc) {
        const int px = wid * 64 + cc * 16 + l15;
        const unsigned hp = (unsigned)(((px >> 5) + 1) * HW + (px & 31) + 1) * TSTRIDE;
        #pragma unroll
        for (int mt = 0; mt < 4; ++mt) {
            xs[cc][mt][0] = ts[hp + mt * 8 + lg * 2];
            xs[cc][mt][1] = ts[hp + mt * 8 + lg * 2 + 1];
        }
    }
    __syncthreads();

    // ---------- Stage A: t = W1 * x via MFMA, in-place (ch, ch+32) bf16 pairs ----------
    for (int chunk = wid; chunk < NCHUNK; chunk += 4) {
        const unsigned base = (unsigned)(chunk * 16 + l15) * TSTRIDE;
        f32x4 acc[4];
        #pragma unroll
        for (int mt = 0; mt < 4; ++mt) acc[mt] = (f32x4)0.0f;
        #pragma unroll
        for (int ks = 0; ks < 2; ++ks) {
            union { unsigned u[4]; short8 s; } bw;
            #pragma unroll
            for (int t = 0; t < 4; ++t) bw.u[t] = ts[base + ks * 16 + lg * 4 + t];
            #pragma unroll
            for (int mt = 0; mt < 4; ++mt)
                acc[mt] = __builtin_amdgcn_mfma_f32_16x16x32_bf16(afrag1[mt][ks], bw.s, acc[mt], 0, 0, 0);
        }
        #pragma unroll
        for (int mt = 0; mt < 2; ++mt) {
            #pragma unroll
            for (int r = 0; r < 4; ++r)
                ts[base + mt * 16 + lg * 4 + r] = cvt_pk_bf16(acc[mt][r], acc[mt + 2][r]);
        }
    }
    __syncthreads();

    // ---------- Stage B: depthwise 3x3 + GELU gate -> vpack[16] (bf16 pairs) ----------
    const int li = tid >> 5, lj = tid & 31;
    unsigned vpack[16];
    #pragma unroll 2
    for (int c2 = 0; c2 < 16; ++c2) {
        const int ca = 2 * c2, cb = 2 * c2 + 1;
        float u1a = 0.0f, u2a = 0.0f, u1b = 0.0f, u2b = 0.0f;
        #pragma unroll
        for (int di = 0; di < 3; ++di) {
            #pragma unroll
            for (int dj = 0; dj < 3; ++dj) {
                const int k = di * 3 + dj;
                const unsigned base = ((li + di) * HW + (lj + dj)) * TSTRIDE + ca;
                const unsigned ua = ts[base];
                const unsigned ub = ts[base + 1];
                u1a = fmaf(wdw[ca * 9 + k],          bf2f_lo(ua), u1a);
                u2a = fmaf(wdw[(ca + HIDC) * 9 + k], bf2f_hi(ua), u2a);
                u1b = fmaf(wdw[cb * 9 + k],          bf2f_lo(ub), u1b);
                u2b = fmaf(wdw[(cb + HIDC) * 9 + k], bf2f_hi(ub), u2b);
            }
        }
        const float va = gelu_f(u1a) * u2a;
        const float vb = gelu_f(u1b) * u2b;
        vpack[c2] = cvt_pk_bf16(va, vb);
    }
    __syncthreads();   // t fully consumed; reuse front of ts for v

    unsigned* vls = ts;   // [256 px][VSTRIDE], words 0..4351
    {
        const unsigned vb_ = (unsigned)tid * VSTRIDE;
        #pragma unroll
        for (int w = 0; w < 16; ++w) vls[vb_ + w] = vpack[w];
    }
    __syncthreads();

    // ---------- Stage D: y = W2 * v via MFMA; add shortcut; store ----------
    float* ob = out + (size_t)b * DIMC * PLANE;
    if (s_ident) {
        #pragma unroll
        for (int cc = 0; cc < 4; ++cc) {
            const int chunk = wid * 4 + cc;
            const int px = chunk * 16 + l15;
            union { unsigned u[4]; short8 s; } bw;
            #pragma unroll
            for (int t = 0; t < 4; ++t) bw.u[t] = vls[(unsigned)px * VSTRIDE + lg * 4 + t];
            const size_t pix = (size_t)(oy + (px >> 5)) * IMW + (ox + (px & 31));
            float* op = ob + pix;
            #pragma unroll
            for (int mt = 0; mt < 4; ++mt) {
                f32x4 acc = __builtin_amdgcn_mfma_f32_16x16x32_bf16(afrag2[mt], bw.s, (f32x4)0.0f, 0, 0, 0);
                #pragma unroll
                for (int r = 0; r < 4; ++r) {
                    const int ch = mt * 16 + lg * 4 + r;
                    const unsigned xw = xs[cc][mt][r >> 1];
                    const float xv = (r & 1) ? bf2f_hi(xw) : bf2f_lo(xw);
                    op[(size_t)ch * PLANE] = acc[r] + xv;
                }
            }
        }
    } else {
        // general path (not hit in bench): 4 passes of 16 channels through ys = ts[8192..]
        float* ys = (float*)(ts + 8192);   // [16][257] floats = 4112 words, no overlap with vls
        for (int mt = 0; mt < 4; ++mt) {
            __syncthreads();
            #pragma unroll
            for (int cc = 0; cc < 4; ++cc) {
                const int chunk = wid * 4 + cc;
                const int px = chunk * 16 + l15;
                union { unsigned u[4]; short8 s; } bw;
                #pragma unroll
                for (int t = 0; t < 4; ++t) bw.u[t] = vls[(unsigned)px * VSTRIDE + lg * 4 + t];
                f32x4 acc = __builtin_amdgcn_mfma_f32_16x16x32_bf16(afrag2[mt], bw.s, (f32x4)0.0f, 0, 0, 0);
                #pragma unroll
                for (int r = 0; r < 4; ++r)
                    ys[(lg * 4 + r) * 257 + px] = acc[r];
            }
            __syncthreads();
            {
                const int chl = tid >> 4;           // 0..15
                const int ch  = mt * 16 + chl;
                const int pt  = tid & 15;           // 2 patch-rows x 8 patch-cols
                const int pi = (pt >> 3) * 4, pj = (pt & 7) * 4;
                float yv[4][4];
                #pragma unroll
                for (int a = 0; a < 4; ++a)
                    #pragma unroll
                    for (int c = 0; c < 4; ++c)
                        yv[a][c] = ys[chl * 257 + (pi + a) * TW + (pj + c)];
                float Cr[4][4], Ci[4][4];
                #pragma unroll
                for (int j = 0; j < 4; ++j) {
                    const float s02 = yv[0][j] + yv[2][j], d02 = yv[0][j] - yv[2][j];
                    const float s13 = yv[1][j] + yv[3][j], d13 = yv[1][j] - yv[3][j];
                    Cr[0][j] = s02 + s13; Ci[0][j] = 0.0f;
                    Cr[1][j] = d02;       Ci[1][j] = -d13;
                    Cr[2][j] = s02 - s13; Ci[2][j] = 0.0f;
                    Cr[3][j] = d02;       Ci[3][j] = d13;
                }
                float Zr[4][3], Zi[4][3];
                #pragma unroll
                for (int u = 0; u < 4; ++u) {
                    const float r0 = Cr[u][0], r1 = Cr[u][1], r2 = Cr[u][2], r3 = Cr[u][3];
                    const float i0 = Ci[u][0], i1 = Ci[u][1], i2 = Ci[u][2], i3 = Ci[u][3];
                    Zr[u][0] = r0 + r1 + r2 + r3;     Zi[u][0] = i0 + i1 + i2 + i3;
                    Zr[u][1] = (r0 - r2) + (i1 - i3); Zi[u][1] = (i0 - i2) - (r1 - r3);
                    Zr[u][2] = r0 - r1 + r2 - r3;     Zi[u][2] = i0 - i1 + i2 - i3;
                    #pragma unroll
                    for (int vv = 0; vv < 3; ++vv) {
                        const float m = wf[ch * 12 + u * 3 + vv];
                        Zr[u][vv] *= m; Zi[u][vv] *= m;
                    }
                }
                float Ar[4][3], Ai[4][3];
                #pragma unroll
                for (int vv = 0; vv < 3; ++vv) {
                    const float r0 = Zr[0][vv], r1 = Zr[1][vv], r2 = Zr[2][vv], r3 = Zr[3][vv];
                    const float i0 = Zi[0][vv], i1 = Zi[1][vv], i2 = Zi[2][vv], i3 = Zi[3][vv];
                    Ar[0][vv] = r0 + r1 + r2 + r3;     Ai[0][vv] = i0 + i1 + i2 + i3;
                    Ar[1][vv] = (r0 - r2) - (i1 - i3); Ai[1][vv] = (i0 - i2) + (r1 - r3);
                    Ar[2][vv] = r0 - r1 + r2 - r3;     Ai[2][vv] = i0 - i1 + i2 - i3;
                    Ar[3][vv] = (r0 - r2) + (i1 - i3); Ai[3][vv] = (i0 - i2) - (r1 - r3);
                }
                const float* xc = xb + (size_t)ch * PLANE;
                float*       oc = ob + (size_t)ch * PLANE;
                #pragma unroll
                for (int a = 0; a < 4; ++a) {
                    const float A0 = Ar[a][0], A1r = Ar[a][1], A2 = Ar[a][2];
                    const float B1i = Ai[a][1];
                    float res[4];
                    res[0] = (A0 + 2.0f * A1r + A2) * 0.0625f;
                    res[1] = (A0 - 2.0f * B1i - A2) * 0.0625f;
                    res[2] = (A0 - 2.0f * A1r + A2) * 0.0625f;
                    res[3] = (A0 + 2.0f * B1i - A2) * 0.0625f;
                    #pragma unroll
                    for (int c = 0; c < 4; ++c) {
                        const size_t pix = (size_t)(oy + pi + a) * IMW + (ox + pj + c);
                        oc[pix] = res[c] + xc[pix];
                    }
                }
            }
        }
    }
}

extern "C" void kernel_launch(void* const* d_in, const int* in_sizes, int n_in,
                              void* d_out, int out_size, void* d_ws, size_t ws_size,
                              hipStream_t stream) {
    (void)in_sizes; (void)n_in; (void)d_ws; (void)ws_size; (void)out_size;
    const float* x   = (const float*)d_in[0];
    const float* w1  = (const float*)d_in[1];
    const float* wdw = (const float*)d_in[2];
    const float* w2  = (const float*)d_in[3];
    const float* wf  = (const float*)d_in[4];
    float* out = (float*)d_out;

    const int blocks = NBATCH * (IMH / TH) * (IMW / TW);  // 4096
    ffn_fused_kernel<<<blocks, 256, 0, stream>>>(x, w1, wdw, w2, wf, out);
}

// Round 6
// 190.969 us; speedup vs baseline: 20.3674x; 1.1150x over previous
//
#include <hip/hip_runtime.h>
#include <hip/hip_fp16.h>
#include <math.h>

#define DIMC 64
#define HIDC 32
#define IMH 512
#define IMW 512
#define TW 32
#define TH 16
#define HW 34
#define HH 18
#define NPIX (HW*HH)     // 612
#define NPIXP 624        // 39 chunks of 16
#define NCHUNK 39
#define PLANE (IMH*IMW)

// d_ws layout (u32 words)
#define IDOFF 0
#define W1OFF 16      // 2048 words: w1 as f16 [64][64]
#define W2OFF 2064    // 1024 words: w2 as f16 [64][32]
#define PWOFF 3088    // 288 words: packed (wdw[ch][k], wdw[ch+32][k]) f16 pairs, [9][32]

typedef _Float16 half8  __attribute__((ext_vector_type(8)));
typedef __fp16   fp16x2 __attribute__((ext_vector_type(2)));
typedef float f32x4     __attribute__((ext_vector_type(4)));
typedef unsigned int uint;

union U4H8 { uint4 u; half8 h; };

static __device__ __forceinline__ uint pkrtz(float a, float b) {
    union { fp16x2 h; uint u; } x;
    x.h = __builtin_amdgcn_cvt_pkrtz(a, b);
    return x.u;
}
static __device__ __forceinline__ float lo16f(uint u) {
    union { uint u; _Float16 h[2]; } x; x.u = u; return (float)x.h[0];
}
static __device__ __forceinline__ float hi16f(uint u) {
    union { uint u; _Float16 h[2]; } x; x.u = u; return (float)x.h[1];
}
static __device__ __forceinline__ uint pkfma(uint w, uint t, uint acc) {
    union { uint u; __half2 h; } W, T, A;
    W.u = w; T.u = t; A.u = acc;
    A.h = __hfma2(W.h, T.h, A.h);
    return A.u;
}

// exact-enough GELU: erf via Abramowitz-Stegun 7.1.26 (|eps| < 1.5e-7), branchless
static __device__ __forceinline__ float gelu_f(float u) {
    const float z  = fabsf(u) * 0.70710678118654752f;
    const float t  = __builtin_amdgcn_rcpf(fmaf(0.3275911f, z, 1.0f));
    const float e  = __builtin_amdgcn_exp2f(-z * z * 1.4426950408889634f);
    float p = fmaf(t, 1.061405429f, -1.453152027f);
    p = fmaf(t, p, 1.421413741f);
    p = fmaf(t, p, -0.284496736f);
    p = fmaf(t, p, 0.254829592f);
    p = p * t;
    const float erf_abs = fmaf(-p, e, 1.0f);
    const float erfv = copysignf(erf_abs, u);
    return 0.5f * u * (1.0f + erfv);
}

// ---------------- prep: pack weights to f16 in d_ws, compute ident flag ----------------
__global__ __launch_bounds__(256)
void ffn_prep(const float* __restrict__ w1, const float* __restrict__ wdw,
              const float* __restrict__ w2, const float* __restrict__ wf,
              uint* __restrict__ ws)
{
    __shared__ int sid;
    const int tid = threadIdx.x;
    if (tid == 0) sid = 1;
    __syncthreads();
    bool ok = true;
    for (int i = tid; i < DIMC * 12; i += 256) ok = ok && (wf[i] == 1.0f);
    if (!ok) atomicAnd(&sid, 0);
    for (int i = tid; i < 2048; i += 256) ws[W1OFF + i] = pkrtz(w1[2*i], w1[2*i+1]);
    for (int i = tid; i < 1024; i += 256) ws[W2OFF + i] = pkrtz(w2[2*i], w2[2*i+1]);
    for (int i = tid; i < 288; i += 256) {
        const int k = i >> 5, ch = i & 31;
        ws[PWOFF + i] = pkrtz(wdw[ch*9 + k], wdw[(ch + HIDC)*9 + k]);
    }
    __syncthreads();
    if (tid == 0) ws[IDOFF] = (uint)sid;
}

// ---------------- main fused kernel ----------------
__global__ __launch_bounds__(512, 4)
void ffn_main(const float* __restrict__ x,
              const uint*  __restrict__ ws,
              const float* __restrict__ wf,
              float* __restrict__ out)
{
    __shared__ uint ts[NPIXP * 32];   // 79872 B; XOR-swizzled halo/t, then v + fallback scratch

    const int tid = threadIdx.x;
    // XCD-chunked bijective swizzle (2048 % 8 == 0)
    const int bid = ((blockIdx.x & 7) << 8) + (blockIdx.x >> 3);
    const int b  = bid >> 9;
    const int tr = bid & 511;
    const int ty = tr >> 4, tx = tr & 15;     // 32 tile-rows x 16 tile-cols
    const int oy = ty * TH, ox = tx * TW;

    const float* xb = x + (size_t)b * DIMC * PLANE;

    // ---------- Stage 0: x halo -> LDS f16 pairs (2c,2c+1), word = px*32 + (w ^ ((px&7)<<2)) ----------
    for (int p = tid; p < NPIXP; p += 512) {
        const int hy = p / HW, hx = p - hy * HW;
        const int gy = oy + hy - 1, gx = ox + hx - 1;
        const uint base = (uint)p << 5, sw = ((uint)p & 7) << 2;
        if (p >= NPIX || (unsigned)gy >= IMH || (unsigned)gx >= IMW) {
            #pragma unroll
            for (int g = 0; g < 8; ++g) {
                uint4 z = {0u, 0u, 0u, 0u};
                *reinterpret_cast<uint4*>(&ts[base + (((uint)g << 2) ^ sw)]) = z;
            }
        } else {
            const float* xp = xb + (size_t)gy * IMW + gx;
            #pragma unroll
            for (int g = 0; g < 8; ++g) {
                float f[8];
                #pragma unroll
                for (int i = 0; i < 8; ++i) f[i] = xp[(size_t)(g * 8 + i) * PLANE];
                uint4 o;
                o.x = pkrtz(f[0], f[1]); o.y = pkrtz(f[2], f[3]);
                o.z = pkrtz(f[4], f[5]); o.w = pkrtz(f[6], f[7]);
                *reinterpret_cast<uint4*>(&ts[base + (((uint)g << 2) ^ sw)]) = o;
            }
        }
    }

    const int lane = tid & 63, wid = tid >> 6;
    const int l15 = lane & 15, lg = lane >> 4;

    // ---------- A-fragments from pre-converted f16 weights ----------
    half8 afrag1[4][2];
    const uint4* w1v = reinterpret_cast<const uint4*>(ws + W1OFF);
    #pragma unroll
    for (int mt = 0; mt < 4; ++mt)
        #pragma unroll
        for (int ks = 0; ks < 2; ++ks) {
            U4H8 u; u.u = w1v[(mt*16 + l15)*8 + ks*4 + lg];
            afrag1[mt][ks] = u.h;
        }
    half8 afrag2[4];
    const uint4* w2v = reinterpret_cast<const uint4*>(ws + W2OFF);
    #pragma unroll
    for (int mt = 0; mt < 4; ++mt) { U4H8 u; u.u = w2v[(mt*16 + l15)*4 + lg]; afrag2[mt] = u.h; }

    const uint ident = ws[IDOFF];
    __syncthreads();

    // ---------- Snapshot shortcut x in store-side layout ----------
    uint xs[4][4][2];
    #pragma unroll
    for (int cc = 0; cc < 4; ++cc) {
        const int px = wid*64 + cc*16 + l15;
        const int h  = ((px >> 5) + 1) * HW + (px & 31) + 1;
        const uint base = (uint)h << 5, sw = ((uint)h & 7) << 2;
        #pragma unroll
        for (int mt = 0; mt < 4; ++mt) {
            const uint a = base + (((uint)(mt*8 + lg*2)) ^ sw);
            xs[cc][mt][0] = ts[a];
            xs[cc][mt][1] = ts[a + 1];
        }
    }
    __syncthreads();

    // ---------- Stage A: t = W1 * x via MFMA f16, in-place (ch, ch+32) pairs ----------
    for (int chunk = wid; chunk < NCHUNK; chunk += 8) {
        const uint px = (uint)(chunk*16 + l15);
        const uint base = px << 5, sw = (px & 7) << 2;
        f32x4 acc[4];
        #pragma unroll
        for (int mt = 0; mt < 4; ++mt) acc[mt] = (f32x4)0.0f;
        #pragma unroll
        for (int ks = 0; ks < 2; ++ks) {
            U4H8 u; u.u = *reinterpret_cast<const uint4*>(&ts[base + (((uint)(ks*16 + lg*4)) ^ sw)]);
            #pragma unroll
            for (int mt = 0; mt < 4; ++mt)
                acc[mt] = __builtin_amdgcn_mfma_f32_16x16x32_f16(afrag1[mt][ks], u.h, acc[mt], 0, 0, 0);
        }
        #pragma unroll
        for (int mt = 0; mt < 2; ++mt) {
            uint4 o;
            o.x = pkrtz(acc[mt][0], acc[mt+2][0]);
            o.y = pkrtz(acc[mt][1], acc[mt+2][1]);
            o.z = pkrtz(acc[mt][2], acc[mt+2][2]);
            o.w = pkrtz(acc[mt][3], acc[mt+2][3]);
            *reinterpret_cast<uint4*>(&ts[base + (((uint)(mt*16 + lg*4)) ^ sw)]) = o;
        }
    }
    __syncthreads();

    // ---------- Stage B: depthwise 3x3 via v_pk_fma_f16, SGPR weights ----------
    const int li = tid >> 5, lj = tid & 31;
    uint acc2[32];
    #pragma unroll
    for (int c = 0; c < 32; ++c) acc2[c] = 0u;
    #pragma unroll
    for (int k = 0; k < 9; ++k) {
        const int di = k / 3, dj = k - di * 3;
        const uint hpx = (uint)((li + di) * HW + (lj + dj));
        const uint base = hpx << 5, sw = (hpx & 7) << 2;
        const uint4* pwv = reinterpret_cast<const uint4*>(ws + PWOFF + k*32);  // uniform -> s_load
        #pragma unroll
        for (int g = 0; g < 8; ++g) {
            const uint4 wv = pwv[g];
            const uint4 tv = *reinterpret_cast<const uint4*>(&ts[base + (((uint)g << 2) ^ sw)]);
            acc2[g*4+0] = pkfma(wv.x, tv.x, acc2[g*4+0]);
            acc2[g*4+1] = pkfma(wv.y, tv.y, acc2[g*4+1]);
            acc2[g*4+2] = pkfma(wv.z, tv.z, acc2[g*4+2]);
            acc2[g*4+3] = pkfma(wv.w, tv.w, acc2[g*4+3]);
        }
    }
    // GELU gate -> packed v (16 words)
    uint4 vo[4];
    #pragma unroll
    for (int gg = 0; gg < 4; ++gg) {
        uint o[4];
        #pragma unroll
        for (int q = 0; q < 4; ++q) {
            const int c2 = gg*4 + q;
            const uint wa = acc2[2*c2], wb = acc2[2*c2 + 1];
            const float v0 = gelu_f(lo16f(wa)) * hi16f(wa);
            const float v1 = gelu_f(lo16f(wb)) * hi16f(wb);
            o[q] = pkrtz(v0, v1);
        }
        vo[gg].x = o[0]; vo[gg].y = o[1]; vo[gg].z = o[2]; vo[gg].w = o[3];
    }
    __syncthreads();   // all t reads complete before v overwrites
    {
        const uint vb = (uint)tid << 4, swv = ((uint)tid & 3) << 2;
        #pragma unroll
        for (int gg = 0; gg < 4; ++gg)
            *reinterpret_cast<uint4*>(&ts[vb + (((uint)gg << 2) ^ swv)]) = vo[gg];
    }
    __syncthreads();

    // ---------- Stage D: y = W2 * v via MFMA; add f16 shortcut; store ----------
    float* ob = out + (size_t)b * DIMC * PLANE;
    if (ident) {
        #pragma unroll
        for (int cc = 0; cc < 4; ++cc) {
            const uint px = (uint)(wid*64 + cc*16 + l15);
            U4H8 u; u.u = *reinterpret_cast<const uint4*>(&ts[(px << 4) + ((((uint)lg ^ (px & 3))) << 2)]);
            const size_t pix = (size_t)(oy + (int)(px >> 5)) * IMW + (ox + (int)(px & 31));
            float* op = ob + pix;
            #pragma unroll
            for (int mt = 0; mt < 4; ++mt) {
                f32x4 a = __builtin_amdgcn_mfma_f32_16x16x32_f16(afrag2[mt], u.h, (f32x4)0.0f, 0, 0, 0);
                #pragma unroll
                for (int r = 0; r < 4; ++r) {
                    const int ch = mt*16 + lg*4 + r;
                    const uint xw = xs[cc][mt][r >> 1];
                    const float xv = (r & 1) ? hi16f(xw) : lo16f(xw);
                    op[(size_t)ch * PLANE] = a[r] + xv;
                }
            }
        }
    } else {
        // general path (not hit in bench): 4 passes of 16 channels; ys disjoint from v region
        float* ys = reinterpret_cast<float*>(ts + 8192);   // [16][520] floats
        for (int mt = 0; mt < 4; ++mt) {
            __syncthreads();
            #pragma unroll
            for (int cc = 0; cc < 4; ++cc) {
                const uint px = (uint)(wid*64 + cc*16 + l15);
                U4H8 u; u.u = *reinterpret_cast<const uint4*>(&ts[(px << 4) + ((((uint)lg ^ (px & 3))) << 2)]);
                f32x4 a = __builtin_amdgcn_mfma_f32_16x16x32_f16(afrag2[mt], u.h, (f32x4)0.0f, 0, 0, 0);
                #pragma unroll
                for (int r = 0; r < 4; ++r)
                    ys[(lg*4 + r) * 520 + (int)px] = a[r];
            }
            __syncthreads();
            {
                const int chl = tid >> 5;            // 0..15
                const int ch  = mt*16 + chl;
                const int pt  = tid & 31;            // 4 patch-rows x 8 patch-cols
                const int pi = (pt >> 3) * 4, pj = (pt & 7) * 4;
                float yv[4][4];
                #pragma unroll
                for (int a = 0; a < 4; ++a)
                    #pragma unroll
                    for (int c = 0; c < 4; ++c)
                        yv[a][c] = ys[chl * 520 + (pi + a) * TW + (pj + c)];
                float Cr[4][4], Ci[4][4];
                #pragma unroll
                for (int j = 0; j < 4; ++j) {
                    const float s02 = yv[0][j] + yv[2][j], d02 = yv[0][j] - yv[2][j];
                    const float s13 = yv[1][j] + yv[3][j], d13 = yv[1][j] - yv[3][j];
                    Cr[0][j] = s02 + s13; Ci[0][j] = 0.0f;
                    Cr[1][j] = d02;       Ci[1][j] = -d13;
                    Cr[2][j] = s02 - s13; Ci[2][j] = 0.0f;
                    Cr[3][j] = d02;       Ci[3][j] = d13;
                }
                float Zr[4][3], Zi[4][3];
                #pragma unroll
                for (int u = 0; u < 4; ++u) {
                    const float r0 = Cr[u][0], r1 = Cr[u][1], r2 = Cr[u][2], r3 = Cr[u][3];
                    const float i0 = Ci[u][0], i1 = Ci[u][1], i2 = Ci[u][2], i3 = Ci[u][3];
                    Zr[u][0] = r0 + r1 + r2 + r3;     Zi[u][0] = i0 + i1 + i2 + i3;
                    Zr[u][1] = (r0 - r2) + (i1 - i3); Zi[u][1] = (i0 - i2) - (r1 - r3);
                    Zr[u][2] = r0 - r1 + r2 - r3;     Zi[u][2] = i0 - i1 + i2 - i3;
                    #pragma unroll
                    for (int vv = 0; vv < 3; ++vv) {
                        const float m = wf[ch * 12 + u * 3 + vv];
                        Zr[u][vv] *= m; Zi[u][vv] *= m;
                    }
                }
                float Ar[4][3], Ai[4][3];
                #pragma unroll
                for (int vv = 0; vv < 3; ++vv) {
                    const float r0 = Zr[0][vv], r1 = Zr[1][vv], r2 = Zr[2][vv], r3 = Zr[3][vv];
                    const float i0 = Zi[0][vv], i1 = Zi[1][vv], i2 = Zi[2][vv], i3 = Zi[3][vv];
                    Ar[0][vv] = r0 + r1 + r2 + r3;     Ai[0][vv] = i0 + i1 + i2 + i3;
                    Ar[1][vv] = (r0 - r2) - (i1 - i3); Ai[1][vv] = (i0 - i2) + (r1 - r3);
                    Ar[2][vv] = r0 - r1 + r2 - r3;     Ai[2][vv] = i0 - i1 + i2 - i3;
                    Ar[3][vv] = (r0 - r2) + (i1 - i3); Ai[3][vv] = (i0 - i2) - (r1 - r3);
                }
                const float* xc = xb + (size_t)ch * PLANE;
                float*       oc = ob + (size_t)ch * PLANE;
                #pragma unroll
                for (int a = 0; a < 4; ++a) {
                    const float A0 = Ar[a][0], A1r = Ar[a][1], A2 = Ar[a][2];
                    const float B1i = Ai[a][1];
                    float res[4];
                    res[0] = (A0 + 2.0f * A1r + A2) * 0.0625f;
                    res[1] = (A0 - 2.0f * B1i - A2) * 0.0625f;
                    res[2] = (A0 - 2.0f * A1r + A2) * 0.0625f;
                    res[3] = (A0 + 2.0f * B1i - A2) * 0.0625f;
                    #pragma unroll
                    for (int c = 0; c < 4; ++c) {
                        const size_t pix = (size_t)(oy + pi + a) * IMW + (ox + pj + c);
                        oc[pix] = res[c] + xc[pix];
                    }
                }
            }
        }
    }
}

extern "C" void kernel_launch(void* const* d_in, const int* in_sizes, int n_in,
                              void* d_out, int out_size, void* d_ws, size_t ws_size,
                              hipStream_t stream) {
    (void)in_sizes; (void)n_in; (void)ws_size; (void)out_size;
    const float* x   = (const float*)d_in[0];
    const float* w1  = (const float*)d_in[1];
    const float* wdw = (const float*)d_in[2];
    const float* w2  = (const float*)d_in[3];
    const float* wf  = (const float*)d_in[4];
    float* out = (float*)d_out;
    uint* ws = (uint*)d_ws;

    ffn_prep<<<1, 256, 0, stream>>>(w1, wdw, w2, wf, ws);
    const int blocks = 4 * (IMH / TH) * (IMW / TW);   // 2048
    ffn_main<<<blocks, 512, 0, stream>>>(x, ws, wf, out);
}